// Round 12
// baseline (206.854 us; speedup 1.0000x reference)
//
#include <hip/hip_runtime.h>
#include <cmath>

namespace {

typedef _Float16 half8 __attribute__((ext_vector_type(8)));
typedef float f32x4 __attribute__((ext_vector_type(4)));

constexpr int M_TOTAL = 32 * 1024;   // B*T
constexpr int K_CH    = 512;
constexpr int NV      = 640;         // G*V
constexpr int D_CV    = 128;
constexpr int NSLOT   = 10;          // 640/64

constexpr int BM = 128, BN = 128, BK = 32;
constexpr int NTILE  = NV / BN;        // 5
constexpr int NPANEL = M_TOTAL / BM;   // 256
constexpr int NBLK   = NTILE * NPANEL; // 1280 (divisible by 8)
constexpr int KT     = K_CH / BK;      // 16

constexpr float LO_SCALE = 4096.0f;    // keep lo-plane f16-normal
constexpr float LO_INV   = 1.0f / 4096.0f;

__device__ __forceinline__ void gld16(const void* g, void* l) {
  __builtin_amdgcn_global_load_lds(
      (__attribute__((address_space(1))) void*)g,
      (__attribute__((address_space(3))) void*)l, 16, 0, 0);
}

// ---------- prep: W[512][640] f32 -> Wth/Wtl [640][512] f16 (k-major) -------
__global__ __launch_bounds__(256)
void prep_w(const float* __restrict__ W, _Float16* __restrict__ Wth,
            _Float16* __restrict__ Wtl)
{
  __shared__ float tile[32][33];
  const int bk = blockIdx.x & 15;
  const int bn = blockIdx.x >> 4;
  const int k0 = bk * 32, n0 = bn * 32;
  const int t = threadIdx.x;
  const int nn = t & 31, kk = t >> 5;
  #pragma unroll
  for (int p = 0; p < 4; ++p)
    tile[kk + p * 8][nn] = W[(size_t)(k0 + kk + p * 8) * NV + n0 + nn];
  __syncthreads();
  const int kx = t & 31, nx = t >> 5;
  #pragma unroll
  for (int p = 0; p < 4; ++p) {
    const float v = tile[kx][nx + p * 8];
    const _Float16 h = (_Float16)v;
    const _Float16 l = (_Float16)((v - (float)h) * LO_SCALE);
    const size_t o = (size_t)(n0 + nx + p * 8) * K_CH + k0 + kx;
    Wth[o] = h;
    Wtl[o] = l;
  }
}

// ---------- main: A staged raw f32, split at frag-read; B f16 planes --------
// r11 skeleton (counted vmcnt(8), 2 barriers/K-step, both-sides swizzle)
// + u/bias register prefetch at kt==KT-3 (lands under ~2 MFMA clusters).
__global__ __launch_bounds__(256, 2)
void gvq_mfma10(const float* __restrict__ x,
                const _Float16* __restrict__ Wth, const _Float16* __restrict__ Wtl,
                const float* __restrict__ bias, const float* __restrict__ u,
                float* __restrict__ pval, int* __restrict__ pidx)
{
  // per buffer (bytes): As f32 [0,16384) | Bh [16384,24576) | Bl [24576,32768)
  __shared__ __align__(16) char lds[2][32768];   // 64 KB

  const int chunk = NBLK / 8;
  const int nid   = (blockIdx.x % 8) * chunk + blockIdx.x / 8;
  const int panel = nid / NTILE, ntile = nid % NTILE;
  const int m0 = panel * BM, n0 = ntile * BN;

  const int t    = threadIdx.x;
  const int wv   = t >> 6, lane = t & 63;
  const int wr   = wv >> 1, wc = wv & 1;      // 2x2 wave grid, 64x64 each
  const int li   = lane & 15, q = lane >> 4;

  // staging source (pre-swizzled global chunk; LDS dest stays linear)
  const int gca = (t & 7) ^ ((t >> 3) & 7);           // A: 16B chunk of 8
  const float* pxa = x + (size_t)(m0 + (t >> 3)) * K_CH + gca * 4;
  const int gcb = (t & 3) ^ ((t >> 3) & 3);           // B: 16B chunk of 4
  const _Float16* pbh = Wth + (size_t)(n0 + (t >> 2)) * K_CH + gcb * 8;
  const _Float16* pbl = Wtl + (size_t)(n0 + (t >> 2)) * K_CH + gcb * 8;

  f32x4 acc1[4][4];   // hi*hi
  f32x4 acc2[4][4];   // hi*lo' + lo'*hi  (lo scaled by 4096)
  #pragma unroll
  for (int i = 0; i < 4; ++i)
    #pragma unroll
    for (int j = 0; j < 4; ++j) {
      acc1[i][j] = (f32x4){0.f, 0.f, 0.f, 0.f};
      acc2[i][j] = (f32x4){0.f, 0.f, 0.f, 0.f};
    }

  auto stage = [&](int kt, int b) {   // 8 gld16 per thread (vmcnt += 8)
    const int ko = kt * BK;
    char* L = lds[b];
    #pragma unroll
    for (int i = 0; i < 4; ++i)
      gld16(pxa + (size_t)i * 32 * K_CH + ko, L + i * 4096 + wv * 1024);
    #pragma unroll
    for (int i = 0; i < 2; ++i) {
      gld16(pbh + (size_t)i * 64 * K_CH + ko, L + 16384 + i * 4096 + wv * 1024);
      gld16(pbl + (size_t)i * 64 * K_CH + ko, L + 24576 + i * 4096 + wv * 1024);
    }
  };

  // frag-read de-swizzled offsets (bytes)
  const int abase = (wr * 64 + li) * 128;              // + fm*2048
  const int s0 = (((q * 2 + 0) ^ (li & 7)) << 4);
  const int s1 = (((q * 2 + 1) ^ (li & 7)) << 4);
  const int bboff = (wc * 64 + li) * 64 + ((q ^ ((li >> 1) & 3)) << 4); // + fn*1024

  // epilogue operand prefetch targets (registers; static indexing only)
  const int colbase = n0 + wc * 64 + li;
  float ureg[4][4][4];
  float bb[4];

  stage(0, 0);
  stage(1, 1);
  #pragma unroll
  for (int kt = 0; kt < KT; ++kt) {
    const int cur = kt & 1;
    // my oldest 8 loads (this tile) done; 8 newer stay in flight
    if (kt < KT - 1) asm volatile("s_waitcnt vmcnt(8)" ::: "memory");
    else             asm volatile("s_waitcnt vmcnt(0)" ::: "memory");
    __builtin_amdgcn_s_barrier();           // everyone's tile-kt loads landed

    const char* L = lds[cur];
    half8 bh[4], bl[4];
    f32x4 af0[4], af1[4];
    #pragma unroll
    for (int fn = 0; fn < 4; ++fn) {
      bh[fn] = *reinterpret_cast<const half8*>(L + 16384 + fn * 1024 + bboff);
      bl[fn] = *reinterpret_cast<const half8*>(L + 24576 + fn * 1024 + bboff);
    }
    #pragma unroll
    for (int fm = 0; fm < 4; ++fm) {
      af0[fm] = *reinterpret_cast<const f32x4*>(L + abase + fm * 2048 + s0);
      af1[fm] = *reinterpret_cast<const f32x4*>(L + abase + fm * 2048 + s1);
    }
    asm volatile("s_waitcnt lgkmcnt(0)" ::: "memory");  // all frags in regs
    __builtin_amdgcn_sched_barrier(0);      // rule #18
    __builtin_amdgcn_s_barrier();           // all reads of buf[cur] done

    if (kt + 2 < KT) stage(kt + 2, cur);    // issue early; flies under MFMA

    if (kt == KT - 3) {
      // prefetch epilogue operands; ~2 MFMA clusters (~3700 cyc) of cover.
      #pragma unroll
      for (int fm = 0; fm < 4; ++fm)
        #pragma unroll
        for (int r = 0; r < 4; ++r) {
          const int m = m0 + wr * 64 + fm * 16 + q * 4 + r;
          #pragma unroll
          for (int fn = 0; fn < 4; ++fn)
            ureg[fm][r][fn] = u[(size_t)m * NV + colbase + fn * 16];
        }
      #pragma unroll
      for (int fn = 0; fn < 4; ++fn) bb[fn] = bias[colbase + fn * 16];
    }

    __builtin_amdgcn_s_setprio(1);
    #pragma unroll
    for (int fm = 0; fm < 4; ++fm) {
      half8 ah, al;                         // split on the fly (== prep_x math)
      #pragma unroll
      for (int e = 0; e < 4; ++e) {
        const float v0 = af0[fm][e], v1 = af1[fm][e];
        const _Float16 h0 = (_Float16)v0, h1 = (_Float16)v1;
        ah[e]     = h0; al[e]     = (_Float16)((v0 - (float)h0) * LO_SCALE);
        ah[4 + e] = h1; al[4 + e] = (_Float16)((v1 - (float)h1) * LO_SCALE);
      }
      #pragma unroll
      for (int fn = 0; fn < 4; ++fn) {
        acc1[fm][fn] = __builtin_amdgcn_mfma_f32_16x16x32_f16(
            ah, bh[fn], acc1[fm][fn], 0, 0, 0);
        acc2[fm][fn] = __builtin_amdgcn_mfma_f32_16x16x32_f16(
            ah, bl[fn], acc2[fm][fn], 0, 0, 0);
        acc2[fm][fn] = __builtin_amdgcn_mfma_f32_16x16x32_f16(
            al, bh[fn], acc2[fm][fn], 0, 0, 0);
      }
    }
    __builtin_amdgcn_s_setprio(0);
  }

  // ---- epilogue: bias + gumbel (fast log), argmax per 64-col slot ----
  // operands already in registers (ureg/bb) — VALU-only from here.
  const int slot = ntile * 2 + wc;
  #pragma unroll
  for (int fm = 0; fm < 4; ++fm) {
    #pragma unroll
    for (int r = 0; r < 4; ++r) {
      const int m = m0 + wr * 64 + fm * 16 + q * 4 + r;
      float bv = -INFINITY;
      int   bi = 0x7fffffff;
      #pragma unroll
      for (int fn = 0; fn < 4; ++fn) {
        const float uu  = ureg[fm][r][fn];
        const float g   = -__logf(-__logf(uu));
        const float val = acc1[fm][fn][r] + acc2[fm][fn][r] * LO_INV
                          + bb[fn] + g;
        const int   n   = colbase + fn * 16;
        if (val > bv) { bv = val; bi = n; }   // fn ascending => first max kept
      }
      #pragma unroll
      for (int s = 1; s <= 8; s <<= 1) {      // reduce over 16 li-lanes
        const float ov = __shfl_xor(bv, s);
        const int   oi = __shfl_xor(bi, s);
        if (ov > bv || (ov == bv && oi < bi)) { bv = ov; bi = oi; }
      }
      if (li == 0) {
        pval[(size_t)m * NSLOT + slot] = bv;
        pidx[(size_t)m * NSLOT + slot] = bi;
      }
    }
  }
}

// ---------- reduce 5 partials per (m,g), gather codevector ----------
__global__ __launch_bounds__(256)
void gvq_gather(const float* __restrict__ pval,
                const int*   __restrict__ pidx,
                const float* __restrict__ cv,
                float* __restrict__ out)
{
  const int tid  = threadIdx.x;
  const int w    = tid >> 6;
  const int lane = tid & 63;
  const int m    = blockIdx.x * 4 + w;
  const int g    = lane >> 5;

  const float* pv = &pval[(size_t)m * NSLOT + g * 5];
  const int*   pi = &pidx[(size_t)m * NSLOT + g * 5];
  float bv = pv[0];
  int   bi = pi[0];
  #pragma unroll
  for (int s = 1; s < 5; ++s) {
    const float v = pv[s];
    const int   i = pi[s];
    if (v > bv || (v == bv && i < bi)) { bv = v; bi = i; }
  }
  const float4 src = *reinterpret_cast<const float4*>(
      &cv[(size_t)bi * D_CV + (lane & 31) * 4]);
  *reinterpret_cast<float4*>(&out[(size_t)m * 256 + lane * 4]) = src;
}

}  // namespace

extern "C" void kernel_launch(void* const* d_in, const int* in_sizes, int n_in,
                              void* d_out, int out_size, void* d_ws, size_t ws_size,
                              hipStream_t stream)
{
  const float* x    = (const float*)d_in[0];
  const float* W    = (const float*)d_in[1];
  const float* bias = (const float*)d_in[2];
  const float* cv   = (const float*)d_in[3];
  const float* u    = (const float*)d_in[4];
  float* out = (float*)d_out;

  _Float16* Wth  = (_Float16*)d_ws;
  _Float16* Wtl  = Wth + (size_t)NV * K_CH;
  float*    pval = (float*)(Wtl + (size_t)NV * K_CH);
  int*      pidx = (int*)(pval + (size_t)M_TOTAL * NSLOT);

  hipLaunchKernelGGL(prep_w, dim3(320), dim3(256), 0, stream, W, Wth, Wtl);
  hipLaunchKernelGGL(gvq_mfma10, dim3(NBLK), dim3(256), 0, stream,
                     x, Wth, Wtl, bias, u, pval, pidx);
  hipLaunchKernelGGL(gvq_gather, dim3(M_TOTAL / 4), dim3(256), 0, stream,
                     pval, pidx, cv, out);
}

// Round 13
// 126.575 us; speedup vs baseline: 1.6342x; 1.6342x over previous
//
#include <hip/hip_runtime.h>
#include <cmath>

namespace {

typedef _Float16 half8 __attribute__((ext_vector_type(8)));
typedef float f32x4 __attribute__((ext_vector_type(4)));

constexpr int M_TOTAL = 32 * 1024;   // B*T
constexpr int K_CH    = 512;
constexpr int NV      = 640;         // G*V
constexpr int D_CV    = 128;
constexpr int NSLOT   = 10;          // 640/64

constexpr int BM = 128, BN = 128, BK = 32;
constexpr int NTILE  = NV / BN;        // 5
constexpr int NPANEL = M_TOTAL / BM;   // 256
constexpr int NBLK   = NTILE * NPANEL; // 1280 (divisible by 8)
constexpr int KT     = K_CH / BK;      // 16

constexpr float LO_SCALE = 4096.0f;    // keep lo-plane f16-normal
constexpr float LO_INV   = 1.0f / 4096.0f;

__device__ __forceinline__ void gld16(const void* g, void* l) {
  __builtin_amdgcn_global_load_lds(
      (__attribute__((address_space(1))) void*)g,
      (__attribute__((address_space(3))) void*)l, 16, 0, 0);
}

// ---------- prep: W[512][640] f32 -> Wth/Wtl [640][512] f16 (k-major) -------
__global__ __launch_bounds__(256)
void prep_w(const float* __restrict__ W, _Float16* __restrict__ Wth,
            _Float16* __restrict__ Wtl)
{
  __shared__ float tile[32][33];
  const int bk = blockIdx.x & 15;
  const int bn = blockIdx.x >> 4;
  const int k0 = bk * 32, n0 = bn * 32;
  const int t = threadIdx.x;
  const int nn = t & 31, kk = t >> 5;
  #pragma unroll
  for (int p = 0; p < 4; ++p)
    tile[kk + p * 8][nn] = W[(size_t)(k0 + kk + p * 8) * NV + n0 + nn];
  __syncthreads();
  const int kx = t & 31, nx = t >> 5;
  #pragma unroll
  for (int p = 0; p < 4; ++p) {
    const float v = tile[kx][nx + p * 8];
    const _Float16 h = (_Float16)v;
    const _Float16 l = (_Float16)((v - (float)h) * LO_SCALE);
    const size_t o = (size_t)(n0 + nx + p * 8) * K_CH + k0 + kx;
    Wth[o] = h;
    Wtl[o] = l;
  }
}

// ---------- main: r11 skeleton + async u-panel staging into dead LDS --------
__global__ __launch_bounds__(256, 2)
void gvq_mfma11(const float* __restrict__ x,
                const _Float16* __restrict__ Wth, const _Float16* __restrict__ Wtl,
                const float* __restrict__ bias, const float* __restrict__ u,
                float* __restrict__ pval, int* __restrict__ pidx)
{
  // per buffer (bytes): As f32 [0,16384) | Bh [16384,24576) | Bl [24576,32768)
  // after the last K-step both buffers are dead -> reused as 128x128 u panel.
  __shared__ __align__(16) char lds[2][32768];   // 64 KB

  const int chunk = NBLK / 8;
  const int nid   = (blockIdx.x % 8) * chunk + blockIdx.x / 8;
  const int panel = nid / NTILE, ntile = nid % NTILE;
  const int m0 = panel * BM, n0 = ntile * BN;

  const int t    = threadIdx.x;
  const int wv   = t >> 6, lane = t & 63;
  const int wr   = wv >> 1, wc = wv & 1;      // 2x2 wave grid, 64x64 each
  const int li   = lane & 15, q = lane >> 4;

  // staging source (pre-swizzled global chunk; LDS dest stays linear)
  const int gca = (t & 7) ^ ((t >> 3) & 7);           // A: 16B chunk of 8
  const float* pxa = x + (size_t)(m0 + (t >> 3)) * K_CH + gca * 4;
  const int gcb = (t & 3) ^ ((t >> 3) & 3);           // B: 16B chunk of 4
  const _Float16* pbh = Wth + (size_t)(n0 + (t >> 2)) * K_CH + gcb * 8;
  const _Float16* pbl = Wtl + (size_t)(n0 + (t >> 2)) * K_CH + gcb * 8;
  // u panel: chunk c = i*256+t -> row c>>5, 16B-chunk c&31 (linear, no swizzle)
  const float* pu0 = u + (size_t)(m0 + (t >> 5)) * NV + n0 + (t & 31) * 4;

  f32x4 acc1[4][4];   // hi*hi
  f32x4 acc2[4][4];   // hi*lo' + lo'*hi  (lo scaled by 4096)
  #pragma unroll
  for (int i = 0; i < 4; ++i)
    #pragma unroll
    for (int j = 0; j < 4; ++j) {
      acc1[i][j] = (f32x4){0.f, 0.f, 0.f, 0.f};
      acc2[i][j] = (f32x4){0.f, 0.f, 0.f, 0.f};
    }

  auto stage = [&](int kt, int b) {   // 8 gld16 per thread (vmcnt += 8)
    const int ko = kt * BK;
    char* L = lds[b];
    #pragma unroll
    for (int i = 0; i < 4; ++i)
      gld16(pxa + (size_t)i * 32 * K_CH + ko, L + i * 4096 + wv * 1024);
    #pragma unroll
    for (int i = 0; i < 2; ++i) {
      gld16(pbh + (size_t)i * 64 * K_CH + ko, L + 16384 + i * 4096 + wv * 1024);
      gld16(pbl + (size_t)i * 64 * K_CH + ko, L + 24576 + i * 4096 + wv * 1024);
    }
  };
  auto stage_u = [&]() {              // 16 gld16: whole 64 KB u panel
    #pragma unroll
    for (int i = 0; i < 16; ++i)
      gld16(pu0 + (size_t)i * 8 * NV, (char*)lds + i * 4096 + wv * 1024);
  };

  // frag-read de-swizzled offsets (bytes)
  const int abase = (wr * 64 + li) * 128;              // + fm*2048
  const int s0 = (((q * 2 + 0) ^ (li & 7)) << 4);
  const int s1 = (((q * 2 + 1) ^ (li & 7)) << 4);
  const int bboff = (wc * 64 + li) * 64 + ((q ^ ((li >> 1) & 3)) << 4); // + fn*1024

  stage(0, 0);
  stage(1, 1);
  #pragma unroll
  for (int kt = 0; kt < KT; ++kt) {
    const int cur = kt & 1;
    // my oldest 8 loads (this tile) done; 8 newer stay in flight
    if (kt < KT - 1) asm volatile("s_waitcnt vmcnt(8)" ::: "memory");
    else             asm volatile("s_waitcnt vmcnt(0)" ::: "memory");
    __builtin_amdgcn_s_barrier();           // everyone's tile-kt loads landed

    const char* L = lds[cur];
    half8 bh[4], bl[4];
    f32x4 af0[4], af1[4];
    #pragma unroll
    for (int fn = 0; fn < 4; ++fn) {
      bh[fn] = *reinterpret_cast<const half8*>(L + 16384 + fn * 1024 + bboff);
      bl[fn] = *reinterpret_cast<const half8*>(L + 24576 + fn * 1024 + bboff);
    }
    #pragma unroll
    for (int fm = 0; fm < 4; ++fm) {
      af0[fm] = *reinterpret_cast<const f32x4*>(L + abase + fm * 2048 + s0);
      af1[fm] = *reinterpret_cast<const f32x4*>(L + abase + fm * 2048 + s1);
    }
    asm volatile("s_waitcnt lgkmcnt(0)" ::: "memory");  // all frags in regs
    __builtin_amdgcn_sched_barrier(0);      // rule #18
    __builtin_amdgcn_s_barrier();           // all reads of buf[cur] done

    if (kt + 2 < KT)      stage(kt + 2, cur);  // issue early; flies under MFMA
    else if (kt == KT - 1) stage_u();          // both buffers dead -> u panel

    __builtin_amdgcn_s_setprio(1);
    #pragma unroll
    for (int fm = 0; fm < 4; ++fm) {
      half8 ah, al;                         // split on the fly (== prep_x math)
      #pragma unroll
      for (int e = 0; e < 4; ++e) {
        const float v0 = af0[fm][e], v1 = af1[fm][e];
        const _Float16 h0 = (_Float16)v0, h1 = (_Float16)v1;
        ah[e]     = h0; al[e]     = (_Float16)((v0 - (float)h0) * LO_SCALE);
        ah[4 + e] = h1; al[4 + e] = (_Float16)((v1 - (float)h1) * LO_SCALE);
      }
      #pragma unroll
      for (int fn = 0; fn < 4; ++fn) {
        acc1[fm][fn] = __builtin_amdgcn_mfma_f32_16x16x32_f16(
            ah, bh[fn], acc1[fm][fn], 0, 0, 0);
        acc2[fm][fn] = __builtin_amdgcn_mfma_f32_16x16x32_f16(
            ah, bl[fn], acc2[fm][fn], 0, 0, 0);
        acc2[fm][fn] = __builtin_amdgcn_mfma_f32_16x16x32_f16(
            al, bh[fn], acc2[fm][fn], 0, 0, 0);
      }
    }
    __builtin_amdgcn_s_setprio(0);
  }

  // u panel landed? my loads drained, then barrier covers all waves' loads.
  asm volatile("s_waitcnt vmcnt(0)" ::: "memory");
  __builtin_amdgcn_s_barrier();

  // ---- epilogue: bias + gumbel (fast log), argmax per 64-col slot ----
  const float* U = (const float*)lds;       // [row 0..127][col 0..127]
  const int colbase = n0 + wc * 64 + li;
  float bb[4];
  #pragma unroll
  for (int fn = 0; fn < 4; ++fn) bb[fn] = bias[colbase + fn * 16];

  const int slot = ntile * 2 + wc;
  #pragma unroll
  for (int fm = 0; fm < 4; ++fm) {
    #pragma unroll
    for (int r = 0; r < 4; ++r) {
      const int m   = m0 + wr * 64 + fm * 16 + q * 4 + r;
      const int urow = wr * 64 + fm * 16 + q * 4 + r;
      float bv = -INFINITY;
      int   bi = 0x7fffffff;
      #pragma unroll
      for (int fn = 0; fn < 4; ++fn) {
        const float uu  = U[urow * 128 + wc * 64 + li + fn * 16];
        const float g   = -__logf(-__logf(uu));
        const float val = acc1[fm][fn][r] + acc2[fm][fn][r] * LO_INV
                          + bb[fn] + g;
        const int   n   = colbase + fn * 16;
        if (val > bv) { bv = val; bi = n; }   // fn ascending => first max kept
      }
      #pragma unroll
      for (int s = 1; s <= 8; s <<= 1) {      // reduce over 16 li-lanes
        const float ov = __shfl_xor(bv, s);
        const int   oi = __shfl_xor(bi, s);
        if (ov > bv || (ov == bv && oi < bi)) { bv = ov; bi = oi; }
      }
      if (li == 0) {
        pval[(size_t)m * NSLOT + slot] = bv;
        pidx[(size_t)m * NSLOT + slot] = bi;
      }
    }
  }
}

// ---------- reduce 5 partials per (m,g), gather codevector ----------
__global__ __launch_bounds__(256)
void gvq_gather(const float* __restrict__ pval,
                const int*   __restrict__ pidx,
                const float* __restrict__ cv,
                float* __restrict__ out)
{
  const int tid  = threadIdx.x;
  const int w    = tid >> 6;
  const int lane = tid & 63;
  const int m    = blockIdx.x * 4 + w;
  const int g    = lane >> 5;

  const float* pv = &pval[(size_t)m * NSLOT + g * 5];
  const int*   pi = &pidx[(size_t)m * NSLOT + g * 5];
  float bv = pv[0];
  int   bi = pi[0];
  #pragma unroll
  for (int s = 1; s < 5; ++s) {
    const float v = pv[s];
    const int   i = pi[s];
    if (v > bv || (v == bv && i < bi)) { bv = v; bi = i; }
  }
  const float4 src = *reinterpret_cast<const float4*>(
      &cv[(size_t)bi * D_CV + (lane & 31) * 4]);
  *reinterpret_cast<float4*>(&out[(size_t)m * 256 + lane * 4]) = src;
}

}  // namespace

extern "C" void kernel_launch(void* const* d_in, const int* in_sizes, int n_in,
                              void* d_out, int out_size, void* d_ws, size_t ws_size,
                              hipStream_t stream)
{
  const float* x    = (const float*)d_in[0];
  const float* W    = (const float*)d_in[1];
  const float* bias = (const float*)d_in[2];
  const float* cv   = (const float*)d_in[3];
  const float* u    = (const float*)d_in[4];
  float* out = (float*)d_out;

  _Float16* Wth  = (_Float16*)d_ws;
  _Float16* Wtl  = Wth + (size_t)NV * K_CH;
  float*    pval = (float*)(Wtl + (size_t)NV * K_CH);
  int*      pidx = (int*)(pval + (size_t)M_TOTAL * NSLOT);

  hipLaunchKernelGGL(prep_w, dim3(320), dim3(256), 0, stream, W, Wth, Wtl);
  hipLaunchKernelGGL(gvq_mfma11, dim3(NBLK), dim3(256), 0, stream,
                     x, Wth, Wtl, bias, u, pval, pidx);
  hipLaunchKernelGGL(gvq_gather, dim3(M_TOTAL / 4), dim3(256), 0, stream,
                     pval, pidx, cv, out);
}

// Round 14
// 123.744 us; speedup vs baseline: 1.6716x; 1.0229x over previous
//
#include <hip/hip_runtime.h>
#include <cmath>

namespace {

typedef _Float16 half8 __attribute__((ext_vector_type(8)));
typedef float f32x4 __attribute__((ext_vector_type(4)));

constexpr int M_TOTAL = 32 * 1024;   // B*T
constexpr int K_CH    = 512;
constexpr int NV      = 640;         // G*V
constexpr int D_CV    = 128;
constexpr int NSLOT   = 10;          // 640/64

constexpr int BM = 128, BN = 128, BK = 32;
constexpr int NTILE  = NV / BN;        // 5
constexpr int NPANEL = M_TOTAL / BM;   // 256
constexpr int NBLK   = NTILE * NPANEL; // 1280 (divisible by 8)
constexpr int KT     = K_CH / BK;      // 16

constexpr float LO_SCALE = 4096.0f;    // keep lo-plane f16-normal
constexpr float LO_INV   = 1.0f / 4096.0f;

__device__ __forceinline__ void gld16(const void* g, void* l) {
  __builtin_amdgcn_global_load_lds(
      (__attribute__((address_space(1))) void*)g,
      (__attribute__((address_space(3))) void*)l, 16, 0, 0);
}

// ---------- prep: W[512][640] f32 -> Wth/Wtl [640][512] f16 (k-major) -------
__global__ __launch_bounds__(256)
void prep_w(const float* __restrict__ W, _Float16* __restrict__ Wth,
            _Float16* __restrict__ Wtl)
{
  __shared__ float tile[32][33];
  const int bk = blockIdx.x & 15;
  const int bn = blockIdx.x >> 4;
  const int k0 = bk * 32, n0 = bn * 32;
  const int t = threadIdx.x;
  const int nn = t & 31, kk = t >> 5;
  #pragma unroll
  for (int p = 0; p < 4; ++p)
    tile[kk + p * 8][nn] = W[(size_t)(k0 + kk + p * 8) * NV + n0 + nn];
  __syncthreads();
  const int kx = t & 31, nx = t >> 5;
  #pragma unroll
  for (int p = 0; p < 4; ++p) {
    const float v = tile[kx][nx + p * 8];
    const _Float16 h = (_Float16)v;
    const _Float16 l = (_Float16)((v - (float)h) * LO_SCALE);
    const size_t o = (size_t)(n0 + nx + p * 8) * K_CH + k0 + kx;
    Wth[o] = h;
    Wtl[o] = l;
  }
}

// ---------- main: r11 skeleton, late barrier-2, compiler-scheduled lgkm -----
// Per K-step: vmcnt(8); barrier; [ds_reads ∥ split ∥ MFMA, compiler-ordered];
// barrier; stage(kt+2). No forced lgkmcnt(0) between reads and MFMA.
__global__ __launch_bounds__(256, 2)
void gvq_mfma12(const float* __restrict__ x,
                const _Float16* __restrict__ Wth, const _Float16* __restrict__ Wtl,
                const float* __restrict__ bias, const float* __restrict__ u,
                float* __restrict__ pval, int* __restrict__ pidx)
{
  // per buffer (bytes): As f32 [0,16384) | Bh [16384,24576) | Bl [24576,32768)
  __shared__ __align__(16) char lds[2][32768];   // 64 KB

  const int chunk = NBLK / 8;
  const int nid   = (blockIdx.x % 8) * chunk + blockIdx.x / 8;
  const int panel = nid / NTILE, ntile = nid % NTILE;
  const int m0 = panel * BM, n0 = ntile * BN;

  const int t    = threadIdx.x;
  const int wv   = t >> 6, lane = t & 63;
  const int wr   = wv >> 1, wc = wv & 1;      // 2x2 wave grid, 64x64 each
  const int li   = lane & 15, q = lane >> 4;

  // staging source (pre-swizzled global chunk; LDS dest stays linear)
  const int gca = (t & 7) ^ ((t >> 3) & 7);           // A: 16B chunk of 8
  const float* pxa = x + (size_t)(m0 + (t >> 3)) * K_CH + gca * 4;
  const int gcb = (t & 3) ^ ((t >> 3) & 3);           // B: 16B chunk of 4
  const _Float16* pbh = Wth + (size_t)(n0 + (t >> 2)) * K_CH + gcb * 8;
  const _Float16* pbl = Wtl + (size_t)(n0 + (t >> 2)) * K_CH + gcb * 8;

  f32x4 acc1[4][4];   // hi*hi
  f32x4 acc2[4][4];   // hi*lo' + lo'*hi  (lo scaled by 4096)
  #pragma unroll
  for (int i = 0; i < 4; ++i)
    #pragma unroll
    for (int j = 0; j < 4; ++j) {
      acc1[i][j] = (f32x4){0.f, 0.f, 0.f, 0.f};
      acc2[i][j] = (f32x4){0.f, 0.f, 0.f, 0.f};
    }

  auto stage = [&](int kt, int b) {   // 8 gld16 per thread (vmcnt += 8)
    const int ko = kt * BK;
    char* L = lds[b];
    #pragma unroll
    for (int i = 0; i < 4; ++i)
      gld16(pxa + (size_t)i * 32 * K_CH + ko, L + i * 4096 + wv * 1024);
    #pragma unroll
    for (int i = 0; i < 2; ++i) {
      gld16(pbh + (size_t)i * 64 * K_CH + ko, L + 16384 + i * 4096 + wv * 1024);
      gld16(pbl + (size_t)i * 64 * K_CH + ko, L + 24576 + i * 4096 + wv * 1024);
    }
  };

  // frag-read de-swizzled offsets (bytes)
  const int abase = (wr * 64 + li) * 128;              // + fm*2048
  const int s0 = (((q * 2 + 0) ^ (li & 7)) << 4);
  const int s1 = (((q * 2 + 1) ^ (li & 7)) << 4);
  const int bboff = (wc * 64 + li) * 64 + ((q ^ ((li >> 1) & 3)) << 4); // + fn*1024

  stage(0, 0);
  stage(1, 1);
  #pragma unroll
  for (int kt = 0; kt < KT; ++kt) {
    const int cur = kt & 1;
    // my oldest 8 loads (this tile) done; 8 newer stay in flight
    if (kt < KT - 1) asm volatile("s_waitcnt vmcnt(8)" ::: "memory");
    else             asm volatile("s_waitcnt vmcnt(0)" ::: "memory");
    __builtin_amdgcn_s_barrier();           // tile kt visible to all waves
    __builtin_amdgcn_sched_barrier(0);      // nothing hoists above the barrier

    const char* L = lds[cur];
    half8 bh[4], bl[4];
    f32x4 af0[4], af1[4];
    #pragma unroll
    for (int fn = 0; fn < 4; ++fn) {
      bh[fn] = *reinterpret_cast<const half8*>(L + 16384 + fn * 1024 + bboff);
      bl[fn] = *reinterpret_cast<const half8*>(L + 24576 + fn * 1024 + bboff);
    }
    #pragma unroll
    for (int fm = 0; fm < 4; ++fm) {
      af0[fm] = *reinterpret_cast<const f32x4*>(L + abase + fm * 2048 + s0);
      af1[fm] = *reinterpret_cast<const f32x4*>(L + abase + fm * 2048 + s1);
    }
    // no lgkmcnt(0): compiler inserts fine-grained waits; MFMA starts as
    // fragments arrive, ds_read latency hides under the cluster.
    #pragma unroll
    for (int fm = 0; fm < 4; ++fm) {
      half8 ah, al;                         // split on the fly (== prep_x math)
      #pragma unroll
      for (int e = 0; e < 4; ++e) {
        const float v0 = af0[fm][e], v1 = af1[fm][e];
        const _Float16 h0 = (_Float16)v0, h1 = (_Float16)v1;
        ah[e]     = h0; al[e]     = (_Float16)((v0 - (float)h0) * LO_SCALE);
        ah[4 + e] = h1; al[4 + e] = (_Float16)((v1 - (float)h1) * LO_SCALE);
      }
      #pragma unroll
      for (int fn = 0; fn < 4; ++fn) {
        acc1[fm][fn] = __builtin_amdgcn_mfma_f32_16x16x32_f16(
            ah, bh[fn], acc1[fm][fn], 0, 0, 0);
        acc2[fm][fn] = __builtin_amdgcn_mfma_f32_16x16x32_f16(
            ah, bl[fn], acc2[fm][fn], 0, 0, 0);
        acc2[fm][fn] = __builtin_amdgcn_mfma_f32_16x16x32_f16(
            al, bh[fn], acc2[fm][fn], 0, 0, 0);
      }
    }
    __builtin_amdgcn_s_barrier();           // all reads of buf[cur] consumed
    __builtin_amdgcn_sched_barrier(0);      // stage stays below the barrier
    if (kt + 2 < KT) stage(kt + 2, cur);    // lands 2 iterations from now
  }

  // ---- epilogue: bias + gumbel (fast log), argmax per 64-col slot ----
  const int colbase = n0 + wc * 64 + li;
  float bb[4];
  #pragma unroll
  for (int fn = 0; fn < 4; ++fn) bb[fn] = bias[colbase + fn * 16];

  const int slot = ntile * 2 + wc;
  #pragma unroll
  for (int fm = 0; fm < 4; ++fm) {
    #pragma unroll
    for (int r = 0; r < 4; ++r) {
      const int m = m0 + wr * 64 + fm * 16 + q * 4 + r;
      float bv = -INFINITY;
      int   bi = 0x7fffffff;
      #pragma unroll
      for (int fn = 0; fn < 4; ++fn) {
        const float uu  = u[(size_t)m * NV + colbase + fn * 16];
        const float g   = -__logf(-__logf(uu));
        const float val = acc1[fm][fn][r] + acc2[fm][fn][r] * LO_INV
                          + bb[fn] + g;
        const int   n   = colbase + fn * 16;
        if (val > bv) { bv = val; bi = n; }   // fn ascending => first max kept
      }
      #pragma unroll
      for (int s = 1; s <= 8; s <<= 1) {      // reduce over 16 li-lanes
        const float ov = __shfl_xor(bv, s);
        const int   oi = __shfl_xor(bi, s);
        if (ov > bv || (ov == bv && oi < bi)) { bv = ov; bi = oi; }
      }
      if (li == 0) {
        pval[(size_t)m * NSLOT + slot] = bv;
        pidx[(size_t)m * NSLOT + slot] = bi;
      }
    }
  }
}

// ---------- reduce 5 partials per (m,g), gather codevector ----------
__global__ __launch_bounds__(256)
void gvq_gather(const float* __restrict__ pval,
                const int*   __restrict__ pidx,
                const float* __restrict__ cv,
                float* __restrict__ out)
{
  const int tid  = threadIdx.x;
  const int w    = tid >> 6;
  const int lane = tid & 63;
  const int m    = blockIdx.x * 4 + w;
  const int g    = lane >> 5;

  const float* pv = &pval[(size_t)m * NSLOT + g * 5];
  const int*   pi = &pidx[(size_t)m * NSLOT + g * 5];
  float bv = pv[0];
  int   bi = pi[0];
  #pragma unroll
  for (int s = 1; s < 5; ++s) {
    const float v = pv[s];
    const int   i = pi[s];
    if (v > bv || (v == bv && i < bi)) { bv = v; bi = i; }
  }
  const float4 src = *reinterpret_cast<const float4*>(
      &cv[(size_t)bi * D_CV + (lane & 31) * 4]);
  *reinterpret_cast<float4*>(&out[(size_t)m * 256 + lane * 4]) = src;
}

}  // namespace

extern "C" void kernel_launch(void* const* d_in, const int* in_sizes, int n_in,
                              void* d_out, int out_size, void* d_ws, size_t ws_size,
                              hipStream_t stream)
{
  const float* x    = (const float*)d_in[0];
  const float* W    = (const float*)d_in[1];
  const float* bias = (const float*)d_in[2];
  const float* cv   = (const float*)d_in[3];
  const float* u    = (const float*)d_in[4];
  float* out = (float*)d_out;

  _Float16* Wth  = (_Float16*)d_ws;
  _Float16* Wtl  = Wth + (size_t)NV * K_CH;
  float*    pval = (float*)(Wtl + (size_t)NV * K_CH);
  int*      pidx = (int*)(pval + (size_t)M_TOTAL * NSLOT);

  hipLaunchKernelGGL(prep_w, dim3(320), dim3(256), 0, stream, W, Wth, Wtl);
  hipLaunchKernelGGL(gvq_mfma12, dim3(NBLK), dim3(256), 0, stream,
                     x, Wth, Wtl, bias, u, pval, pidx);
  hipLaunchKernelGGL(gvq_gather, dim3(M_TOTAL / 4), dim3(256), 0, stream,
                     pval, pidx, cv, out);
}

// Round 15
// 122.307 us; speedup vs baseline: 1.6913x; 1.0117x over previous
//
#include <hip/hip_runtime.h>
#include <cmath>

namespace {

typedef _Float16 half8 __attribute__((ext_vector_type(8)));
typedef float f32x4 __attribute__((ext_vector_type(4)));

constexpr int M_TOTAL = 32 * 1024;   // B*T
constexpr int K_CH    = 512;
constexpr int NV      = 640;         // G*V
constexpr int D_CV    = 128;
constexpr int NSLOT   = 10;          // 640/64

constexpr int BM = 128, BN = 128, BK = 32;
constexpr int NTILE  = NV / BN;        // 5
constexpr int NPANEL = M_TOTAL / BM;   // 256
constexpr int NBLK   = NTILE * NPANEL; // 1280 (divisible by 8)
constexpr int KT     = K_CH / BK;      // 16

// Asymmetric split scaling: lo planes x64 (f16-normal), opposing hi /64
// (exact exponent shift) => all three products land at TRUE scale ->
// single accumulator (64 VGPRs freed vs dual-acc).
constexpr float LO_UP = 64.0f;

__device__ __forceinline__ void gld16(const void* g, void* l) {
  __builtin_amdgcn_global_load_lds(
      (__attribute__((address_space(1))) void*)g,
      (__attribute__((address_space(3))) void*)l, 16, 0, 0);
}

// ---------- prep: W[512][640] f32 -> Wth/Wtl [640][512] f16 (k-major) -------
__global__ __launch_bounds__(256)
void prep_w(const float* __restrict__ W, _Float16* __restrict__ Wth,
            _Float16* __restrict__ Wtl)
{
  __shared__ float tile[32][33];
  const int bk = blockIdx.x & 15;
  const int bn = blockIdx.x >> 4;
  const int k0 = bk * 32, n0 = bn * 32;
  const int t = threadIdx.x;
  const int nn = t & 31, kk = t >> 5;
  #pragma unroll
  for (int p = 0; p < 4; ++p)
    tile[kk + p * 8][nn] = W[(size_t)(k0 + kk + p * 8) * NV + n0 + nn];
  __syncthreads();
  const int kx = t & 31, nx = t >> 5;
  #pragma unroll
  for (int p = 0; p < 4; ++p) {
    const float v = tile[kx][nx + p * 8];
    const _Float16 h = (_Float16)v;
    const _Float16 l = (_Float16)((v - (float)h) * LO_UP);
    const size_t o = (size_t)(n0 + nx + p * 8) * K_CH + k0 + kx;
    Wth[o] = h;
    Wtl[o] = l;
  }
}

// ---------- main: single-accumulator split-f16 MFMA GEMM --------------------
__global__ __launch_bounds__(256, 2)
void gvq_mfma13(const float* __restrict__ x,
                const _Float16* __restrict__ Wth, const _Float16* __restrict__ Wtl,
                const float* __restrict__ bias, const float* __restrict__ u,
                float* __restrict__ pval, int* __restrict__ pidx)
{
  // per buffer (bytes): As f32 [0,16384) | Bh [16384,24576) | Bl [24576,32768)
  __shared__ __align__(16) char lds[2][32768];   // 64 KB

  const int chunk = NBLK / 8;
  const int nid   = (blockIdx.x % 8) * chunk + blockIdx.x / 8;
  const int panel = nid / NTILE, ntile = nid % NTILE;
  const int m0 = panel * BM, n0 = ntile * BN;

  const int t    = threadIdx.x;
  const int wv   = t >> 6, lane = t & 63;
  const int wr   = wv >> 1, wc = wv & 1;      // 2x2 wave grid, 64x64 each
  const int li   = lane & 15, q = lane >> 4;

  // staging source (pre-swizzled global chunk; LDS dest stays linear)
  const int gca = (t & 7) ^ ((t >> 3) & 7);           // A: 16B chunk of 8
  const float* pxa = x + (size_t)(m0 + (t >> 3)) * K_CH + gca * 4;
  const int gcb = (t & 3) ^ ((t >> 3) & 3);           // B: 16B chunk of 4
  const _Float16* pbh = Wth + (size_t)(n0 + (t >> 2)) * K_CH + gcb * 8;
  const _Float16* pbl = Wtl + (size_t)(n0 + (t >> 2)) * K_CH + gcb * 8;

  f32x4 acc[4][4];    // single accumulator (true scale)
  #pragma unroll
  for (int i = 0; i < 4; ++i)
    #pragma unroll
    for (int j = 0; j < 4; ++j)
      acc[i][j] = (f32x4){0.f, 0.f, 0.f, 0.f};

  auto stage = [&](int kt, int b) {   // 8 gld16 per thread (vmcnt += 8)
    const int ko = kt * BK;
    char* L = lds[b];
    #pragma unroll
    for (int i = 0; i < 4; ++i)
      gld16(pxa + (size_t)i * 32 * K_CH + ko, L + i * 4096 + wv * 1024);
    #pragma unroll
    for (int i = 0; i < 2; ++i) {
      gld16(pbh + (size_t)i * 64 * K_CH + ko, L + 16384 + i * 4096 + wv * 1024);
      gld16(pbl + (size_t)i * 64 * K_CH + ko, L + 24576 + i * 4096 + wv * 1024);
    }
  };

  // frag-read de-swizzled offsets (bytes)
  const int abase = (wr * 64 + li) * 128;              // + fm*2048
  const int s0 = (((q * 2 + 0) ^ (li & 7)) << 4);
  const int s1 = (((q * 2 + 1) ^ (li & 7)) << 4);
  const int bboff = (wc * 64 + li) * 64 + ((q ^ ((li >> 1) & 3)) << 4); // + fn*1024

  const int colbase = n0 + wc * 64 + li;
  const _Float16 hd = (_Float16)(1.0f / 64.0f);
  float ureg[4][4][4];   // prefetched in last K-step (bounded live range)
  float bb[4];

  stage(0, 0);
  stage(1, 1);
  #pragma unroll
  for (int kt = 0; kt < KT; ++kt) {
    const int cur = kt & 1;
    if (kt < KT - 1) asm volatile("s_waitcnt vmcnt(8)" ::: "memory");
    else             asm volatile("s_waitcnt vmcnt(0)" ::: "memory");
    __builtin_amdgcn_s_barrier();           // tile kt visible to all waves
    __builtin_amdgcn_sched_barrier(0);      // nothing hoists above the barrier

    const char* L = lds[cur];
    half8 bh[4], bl[4], bhd[4];
    f32x4 af0[4], af1[4];
    #pragma unroll
    for (int fn = 0; fn < 4; ++fn) {
      bh[fn] = *reinterpret_cast<const half8*>(L + 16384 + fn * 1024 + bboff);
      bl[fn] = *reinterpret_cast<const half8*>(L + 24576 + fn * 1024 + bboff);
    }
    #pragma unroll
    for (int fm = 0; fm < 4; ++fm) {
      af0[fm] = *reinterpret_cast<const f32x4*>(L + abase + fm * 2048 + s0);
      af1[fm] = *reinterpret_cast<const f32x4*>(L + abase + fm * 2048 + s1);
    }

    if (kt == KT - 1) {
      // epilogue operand prefetch: flies under the final MFMA cluster.
      #pragma unroll
      for (int fm = 0; fm < 4; ++fm)
        #pragma unroll
        for (int r = 0; r < 4; ++r) {
          const int m = m0 + wr * 64 + fm * 16 + q * 4 + r;
          #pragma unroll
          for (int fn = 0; fn < 4; ++fn)
            ureg[fm][r][fn] = u[(size_t)m * NV + colbase + fn * 16];
        }
      #pragma unroll
      for (int fn = 0; fn < 4; ++fn) bb[fn] = bias[colbase + fn * 16];
    }

    #pragma unroll
    for (int fn = 0; fn < 4; ++fn) {
      half8 d;
      #pragma unroll
      for (int e = 0; e < 8; ++e) d[e] = bh[fn][e] * hd;   // exact /64
      bhd[fn] = d;
    }
    #pragma unroll
    for (int fm = 0; fm < 4; ++fm) {
      half8 ah, al, ahd;                    // split on the fly
      #pragma unroll
      for (int e = 0; e < 4; ++e) {
        const float v0 = af0[fm][e], v1 = af1[fm][e];
        const _Float16 h0 = (_Float16)v0, h1 = (_Float16)v1;
        ah[e]      = h0; al[e]      = (_Float16)((v0 - (float)h0) * LO_UP);
        ah[4 + e]  = h1; al[4 + e]  = (_Float16)((v1 - (float)h1) * LO_UP);
        ahd[e]     = h0 * hd;
        ahd[4 + e] = h1 * hd;
      }
      #pragma unroll
      for (int fn = 0; fn < 4; ++fn) {
        acc[fm][fn] = __builtin_amdgcn_mfma_f32_16x16x32_f16(
            ah, bh[fn], acc[fm][fn], 0, 0, 0);        // hi*hi
        acc[fm][fn] = __builtin_amdgcn_mfma_f32_16x16x32_f16(
            ahd, bl[fn], acc[fm][fn], 0, 0, 0);       // (h/64)*(64*lo_w)
        acc[fm][fn] = __builtin_amdgcn_mfma_f32_16x16x32_f16(
            al, bhd[fn], acc[fm][fn], 0, 0, 0);       // (64*lo_x)*(h_w/64)
      }
    }
    if (kt + 2 < KT) {
      __builtin_amdgcn_s_barrier();         // all reads of buf[cur] consumed
      __builtin_amdgcn_sched_barrier(0);    // stage stays below the barrier
      stage(kt + 2, cur);                   // lands 2 iterations from now
    }
  }

  // ---- epilogue: bias + gumbel (fast log), argmax per 64-col slot ----
  const int slot = ntile * 2 + wc;
  #pragma unroll
  for (int fm = 0; fm < 4; ++fm) {
    #pragma unroll
    for (int r = 0; r < 4; ++r) {
      const int m = m0 + wr * 64 + fm * 16 + q * 4 + r;
      float bv = -INFINITY;
      int   bi = 0x7fffffff;
      #pragma unroll
      for (int fn = 0; fn < 4; ++fn) {
        const float uu  = ureg[fm][r][fn];
        const float g   = -__logf(-__logf(uu));
        const float val = acc[fm][fn][r] + bb[fn] + g;
        const int   n   = colbase + fn * 16;
        if (val > bv) { bv = val; bi = n; }   // fn ascending => first max kept
      }
      #pragma unroll
      for (int s = 1; s <= 8; s <<= 1) {      // reduce over 16 li-lanes
        const float ov = __shfl_xor(bv, s);
        const int   oi = __shfl_xor(bi, s);
        if (ov > bv || (ov == bv && oi < bi)) { bv = ov; bi = oi; }
      }
      if (li == 0) {
        pval[(size_t)m * NSLOT + slot] = bv;
        pidx[(size_t)m * NSLOT + slot] = bi;
      }
    }
  }
}

// ---------- reduce 5 partials per (m,g), gather codevector ----------
__global__ __launch_bounds__(256)
void gvq_gather(const float* __restrict__ pval,
                const int*   __restrict__ pidx,
                const float* __restrict__ cv,
                float* __restrict__ out)
{
  const int tid  = threadIdx.x;
  const int w    = tid >> 6;
  const int lane = tid & 63;
  const int m    = blockIdx.x * 4 + w;
  const int g    = lane >> 5;

  const float* pv = &pval[(size_t)m * NSLOT + g * 5];
  const int*   pi = &pidx[(size_t)m * NSLOT + g * 5];
  float bv = pv[0];
  int   bi = pi[0];
  #pragma unroll
  for (int s = 1; s < 5; ++s) {
    const float v = pv[s];
    const int   i = pi[s];
    if (v > bv || (v == bv && i < bi)) { bv = v; bi = i; }
  }
  const float4 src = *reinterpret_cast<const float4*>(
      &cv[(size_t)bi * D_CV + (lane & 31) * 4]);
  *reinterpret_cast<float4*>(&out[(size_t)m * 256 + lane * 4]) = src;
}

}  // namespace

extern "C" void kernel_launch(void* const* d_in, const int* in_sizes, int n_in,
                              void* d_out, int out_size, void* d_ws, size_t ws_size,
                              hipStream_t stream)
{
  const float* x    = (const float*)d_in[0];
  const float* W    = (const float*)d_in[1];
  const float* bias = (const float*)d_in[2];
  const float* cv   = (const float*)d_in[3];
  const float* u    = (const float*)d_in[4];
  float* out = (float*)d_out;

  _Float16* Wth  = (_Float16*)d_ws;
  _Float16* Wtl  = Wth + (size_t)NV * K_CH;
  float*    pval = (float*)(Wtl + (size_t)NV * K_CH);
  int*      pidx = (int*)(pval + (size_t)M_TOTAL * NSLOT);

  hipLaunchKernelGGL(prep_w, dim3(320), dim3(256), 0, stream, W, Wth, Wtl);
  hipLaunchKernelGGL(gvq_mfma13, dim3(NBLK), dim3(256), 0, stream,
                     x, Wth, Wtl, bias, u, pval, pidx);
  hipLaunchKernelGGL(gvq_gather, dim3(M_TOTAL / 4), dim3(256), 0, stream,
                     pval, pidx, cv, out);
}